// Round 19
// baseline (58.716 us; speedup 1.0000x reference)
//
#include <hip/hip_runtime.h>
#include <stdint.h>

#define RH 224
#define RW 224
#define HW (RH * RW)                   // 50176 pixels
#define NCHUNK 16                      // chunks per batch; local order < 2^16
#define BLOCK_THREADS 1024
#define LDSW (HW / 2)                  // 25088 u32 words = full u16 image
#define SPX (HW / 2)                   // 25088 pixels per stripe
#define SWORDS (SPX / 2)               // 12544 u32 words per stripe (50176 B)

// FP policy (FROZEN — bit-exact vs ref=np since round 8, absmax 0.0):
// numpy f32 einsum scalar tail: FORWARD accumulation, separate mul/add
// rounds, no FMA; all later elementwise ops separately rounded.
// `#pragma clang fp contract(off)` everywhere FP happens.
//
// Perf history:
//  r8 389us global atomics | r9 739us guard-load REGRESS | r10 81us LDS
//  stripes x4 | r11 57us stripes x2 | r12 68us stripes x3 REGRESS |
//  r13 78us proj-once+atomic-flush REGRESS | r14 60us ws-staged flush |
//  r15 48us full-image u16 LDS CAS project-once | r16 47.4us resolve
//  vectorize (BEST) | r17 50.0us 8pt-ILP+optimistic-CAS REGRESS |
//  r18 50.8us phase-split @1blk/CU REGRESS. ILP is NOT the limiter.
//  r19: occupancy play — 50KB u16 stripe buffer + reg-cached codes
//  (Pass A project once; Pass B scatter per stripe), launch_bounds
//  (1024,8) pins VGPR<=64 -> 2 blocks/CU = 8 waves/SIMD (2x hiding).
//  ws layout unchanged (stripe halves contiguous) -> resolve16 as-is.

#pragma clang fp contract(off)

__device__ __forceinline__ float dot3_fwd_nofma(float v0, float v1, float v2,
                                                float R0, float R1, float R2,
                                                float t) {
#pragma clang fp contract(off)
    const float p0 = v0 * R0;
    const float p1 = v1 * R1;
    const float p2 = v2 * R2;
    float acc = p0 + p1;
    acc = acc + p2;
    acc = acc + t;
    return acc;
}

// ---------------- fast path: project once, u16 stripe z-buffer -------------
__global__ __launch_bounds__(BLOCK_THREADS, 8) void
proj16_kernel(const float* __restrict__ vertices,
              const float* __restrict__ rotation,
              const float* __restrict__ translation,
              const float* __restrict__ Kmat,
              unsigned int* __restrict__ ws,   // staged u16 images (as u32)
              int N, int chunk) {
#pragma clang fp contract(off)
    extern __shared__ unsigned int sbuf[];     // SWORDS u32 = 50176 B

    const int blk = (int)blockIdx.x;           // blk = b*NCHUNK + c
    const int c   = blk % NCHUNK;
    const int b   = blk / NCHUNK;
    const int tid = (int)threadIdx.x;

    // Per-batch params (block-uniform -> scalar regs).
    const float* R = rotation + b * 9;
    const float* t = translation + b * 3;
    const float* k = Kmat + b * 9;
    const float fx = k[0], cx = k[2], fy = k[4], cy = k[5];
    const float R00 = R[0], R01 = R[1], R02 = R[2];
    const float R10 = R[3], R11 = R[4], R12 = R[5];
    const float R20 = R[6], R21 = R[7], R22 = R[8];
    const float t0 = t[0], t1 = t[1], t2 = t[2];

    const int n_beg  = c * chunk;              // chunk % 4 == 0 -> aligned
    const int n_end  = min(N, n_beg + chunk);
    const int nquads = (n_end - n_beg + 3) >> 2;

    // ---- Pass A: pure projection math; pack pixel codes 2xu16/VGPR. ----
    // Quad j covers points n_beg + (j*1024+tid)*4 + kk; code 0xFFFF = invalid.
    unsigned int pix[16];
#pragma unroll
    for (int j = 0; j < 8; ++j) {
        unsigned int lo = 0xFFFFu | (0xFFFFu << 16);
        unsigned int hi = 0xFFFFu | (0xFFFFu << 16);
        const int q = j * BLOCK_THREADS + tid;
        if (q < nquads) {
            const int n0 = n_beg + (q << 2);
            const float4* vp =
                (const float4*)(vertices + ((size_t)b * N + n0) * 3);
            const float4 f0 = vp[0], f1 = vp[1], f2 = vp[2];
            const float pxv[4][3] = {{f0.x, f0.y, f0.z}, {f0.w, f1.x, f1.y},
                                     {f1.z, f1.w, f2.x}, {f2.y, f2.z, f2.w}};
            unsigned int code[4];
#pragma unroll
            for (int kk = 0; kk < 4; ++kk) {
                code[kk] = 0xFFFFu;
                const int n = n0 + kk;
                if (n >= n_end) continue;
                const float v0 = pxv[kk][0], v1 = pxv[kk][1], v2 = pxv[kk][2];

                // FROZEN FP ORDER (single exact projection per point).
                const float y = dot3_fwd_nofma(v0, v1, v2, R10, R11, R12, t1);
                const float z = dot3_fwd_nofma(v0, v1, v2, R20, R21, R22, t2);
                const float Z = z + 1e-8f;          // separate round
                const float qy = y / Z;             // correctly-rounded div
                float w = fy * qy;                  // separate mul
                w = w + cy;                         // separate add
                const float tv = truncf(w);
                if (!(tv >= 0.0f && tv < (float)RH)) continue;  // NaN -> skip

                const float x = dot3_fwd_nofma(v0, v1, v2, R00, R01, R02, t0);
                const float qx = x / Z;
                float u = fx * qx;
                u = u + cx;
                const float tu = truncf(u);
                if (!(tu >= 0.0f && tu < (float)RW)) continue;

                code[kk] = (unsigned int)((int)tv * RW + (int)tu);  // < 50176
            }
            lo = code[0] | (code[1] << 16);
            hi = code[2] | (code[3] << 16);
        }
        pix[2 * j + 0] = lo;
        pix[2 * j + 1] = hi;
    }

    // ---- Pass B: per stripe {zero, scatter cached codes, flush}. ----
    for (int s = 0; s < 2; ++s) {
        const unsigned int p_lo = (unsigned int)(s * SPX);
        const unsigned int p_hi = p_lo + (unsigned int)SPX;

        {
            uint4* s4 = (uint4*)sbuf;
            const uint4 z = {0u, 0u, 0u, 0u};
            for (int j = tid; j < SWORDS / 4; j += BLOCK_THREADS) s4[j] = z;
        }
        __syncthreads();

#pragma unroll
        for (int m = 0; m < 16; ++m) {
            const int j  = m >> 1;
            const int kb = (m & 1) << 1;           // kk base: 0 or 2
            const unsigned int pk = pix[m];
            const unsigned int vbase =
                (unsigned int)(j * (BLOCK_THREADS * 4) + tid * 4) + 1u;
#pragma unroll
            for (int h = 0; h < 2; ++h) {
                const unsigned int p = (h == 0) ? (pk & 0xFFFFu) : (pk >> 16);
                if (!(p >= p_lo && p < p_hi)) continue;   // 0xFFFF fails both
                const unsigned int slot = p - p_lo;
                const unsigned int sh   = (slot & 1u) << 4;
                const unsigned int msk  = 0xFFFFu << sh;
                const unsigned int val  = vbase + (unsigned int)(kb + h);
                unsigned int* wp = &sbuf[slot >> 1];
                unsigned int cur = *wp;               // proven r16 protocol
                while (((cur >> sh) & 0xFFFFu) < val) {
                    const unsigned int nw = (cur & ~msk) | (val << sh);
                    const unsigned int prev = atomicCAS(wp, cur, nw);
                    if (prev == cur) break;
                    cur = prev;
                }
            }
        }
        __syncthreads();

        // Flush stripe to its half of this block's ws slice (layout matches
        // the full-image resolve: word offset s*SWORDS).
        uint4* dst = (uint4*)(ws + (size_t)blk * LDSW + (size_t)s * SWORDS);
        const uint4* src = (const uint4*)sbuf;
        for (int j = tid; j < SWORDS / 4; j += BLOCK_THREADS)
            dst[j] = src[j];
        __syncthreads();   // protect re-zero next stripe
    }
}

// Resolve: 4 pixels/thread. Scan copies in ASCENDING chunk order; a nonzero
// later copy strictly wins -> conditional overwrite. Decode n, recompute
// depth with the frozen FP sequence.
__global__ void resolve16_kernel(const unsigned short* __restrict__ ws16,
                                 const float* __restrict__ vertices,
                                 const float* __restrict__ rotation,
                                 const float* __restrict__ translation,
                                 float* __restrict__ out, int N, int chunk,
                                 int P) {
#pragma clang fp contract(off)
    const int g = blockIdx.x * blockDim.x + threadIdx.x;   // 4-pixel group
    if (g >= P / 4) return;
    const int i0  = g << 2;
    const int b   = i0 / HW;
    const int pix = i0 - b * HW;                 // multiple of 4

    const unsigned short* base = ws16 + ((size_t)b * NCHUNK) * HW + pix;
    unsigned int m0 = 0u, m1 = 0u, m2 = 0u, m3 = 0u;
#pragma unroll
    for (int cc = 0; cc < NCHUNK; ++cc) {
        const uint2 v2 = *(const uint2*)(base + (size_t)cc * HW);
        const unsigned int ck = (unsigned int)(cc + 1) << 16;
        unsigned int v;
        v = v2.x & 0xFFFFu; if (v) m0 = ck | v;
        v = v2.x >> 16;     if (v) m1 = ck | v;
        v = v2.y & 0xFFFFu; if (v) m2 = ck | v;
        v = v2.y >> 16;     if (v) m3 = ck | v;
    }

    const unsigned int mm[4] = {m0, m1, m2, m3};
    float4 o;
    float* op = (float*)&o;
#pragma unroll
    for (int j = 0; j < 4; ++j) {
        float depth = 0.0f;
        const unsigned int m = mm[j];
        if (m != 0u) {
            const int cc = (int)(m >> 16) - 1;
            const int n  = cc * chunk + (int)(m & 0xFFFFu) - 1;
            const float* v = vertices + ((size_t)b * (size_t)N + (size_t)n) * 3;
            const float* R = rotation + b * 9;
            depth = dot3_fwd_nofma(v[0], v[1], v[2], R[6], R[7], R[8],
                                   translation[b * 3 + 2]);
        }
        op[j] = depth;
    }
    *(float4*)(out + i0) = o;
}

// ---------------- fallback path (r11: u32 LDS stripes + atomic flush) ------
#define NSTRIPE 2
#define STRIPE_ROWS (RH / NSTRIPE)
#define STRIPE_PX (STRIPE_ROWS * RW)

__global__ __launch_bounds__(BLOCK_THREADS) void
proj_fb_kernel(const float* __restrict__ vertices,
               const float* __restrict__ rotation,
               const float* __restrict__ translation,
               const float* __restrict__ Kmat,
               unsigned int* __restrict__ win, int N) {
#pragma clang fp contract(off)
    extern __shared__ unsigned int sbuf[];
    const int blk = (int)blockIdx.x;
    const int s   = blk & (NSTRIPE - 1);
    const int c   = (blk >> 1) & 7;
    const int b   = blk >> 4;
    for (int j = threadIdx.x; j < STRIPE_PX; j += BLOCK_THREADS) sbuf[j] = 0u;
    __syncthreads();
    const float* R = rotation + b * 9;
    const float* t = translation + b * 3;
    const float* k = Kmat + b * 9;
    const float fx = k[0], cx = k[2], fy = k[4], cy = k[5];
    const float R00 = R[0], R01 = R[1], R02 = R[2];
    const float R10 = R[3], R11 = R[4], R12 = R[5];
    const float R20 = R[6], R21 = R[7], R22 = R[8];
    const float t0 = t[0], t1 = t[1], t2 = t[2];
    const int chunk  = (N + 7) / 8;
    const int n_beg  = c * chunk;
    const int n_end  = min(N, n_beg + chunk);
    const int nquads = (n_end - n_beg + 3) >> 2;
    const float v_lo = (float)(s * STRIPE_ROWS);
    const float v_hi = (float)((s + 1) * STRIPE_ROWS);
    for (int q = threadIdx.x; q < nquads; q += BLOCK_THREADS) {
        const int n0 = n_beg + (q << 2);
        const float4* vp = (const float4*)(vertices + ((size_t)b * N + n0) * 3);
        const float4 f0 = vp[0], f1 = vp[1], f2 = vp[2];
        const float pxv[4][3] = {{f0.x, f0.y, f0.z}, {f0.w, f1.x, f1.y},
                                 {f1.z, f1.w, f2.x}, {f2.y, f2.z, f2.w}};
#pragma unroll
        for (int kk = 0; kk < 4; ++kk) {
            const int n = n0 + kk;
            if (n >= n_end) break;
            const float v0 = pxv[kk][0], v1 = pxv[kk][1], v2 = pxv[kk][2];
            const float y = dot3_fwd_nofma(v0, v1, v2, R10, R11, R12, t1);
            const float z = dot3_fwd_nofma(v0, v1, v2, R20, R21, R22, t2);
            const float Z = z + 1e-8f;
            const float qy = y / Z;
            float w = fy * qy;
            w = w + cy;
            const float tv = truncf(w);
            if (!(tv >= v_lo && tv < v_hi)) continue;
            const float x = dot3_fwd_nofma(v0, v1, v2, R00, R01, R02, t0);
            const float qx = x / Z;
            float u = fx * qx;
            u = u + cx;
            const float tu = truncf(u);
            if (!(tu >= 0.0f && tu < (float)RW)) continue;
            const int slot = ((int)tv - s * STRIPE_ROWS) * RW + (int)tu;
            atomicMax(&sbuf[slot], (unsigned int)(b * N + n) + 1u);
        }
    }
    __syncthreads();
    unsigned int* g = win + b * HW + s * STRIPE_PX;
    for (int j = threadIdx.x; j < STRIPE_PX; j += BLOCK_THREADS) {
        const unsigned int val = sbuf[j];
        if (val) atomicMax(&g[j], val);
    }
}

__global__ void resolve_fb_kernel(unsigned int* __restrict__ buf,
                                  const float* __restrict__ vertices,
                                  const float* __restrict__ rotation,
                                  const float* __restrict__ translation,
                                  int N, int P) {
#pragma clang fp contract(off)
    const int i = blockIdx.x * blockDim.x + threadIdx.x;
    if (i >= P) return;
    const unsigned int o1 = buf[i];
    float depth = 0.0f;
    if (o1 != 0u) {
        const unsigned int o = o1 - 1u;
        const int b = (int)(o / (unsigned int)N);
        const int n = (int)(o % (unsigned int)N);
        const float* v = vertices + ((size_t)b * (size_t)N + (size_t)n) * 3;
        const float* R = rotation + b * 9;
        depth = dot3_fwd_nofma(v[0], v[1], v[2], R[6], R[7], R[8],
                               translation[b * 3 + 2]);
    }
    buf[i] = __float_as_uint(depth);
}

extern "C" void kernel_launch(void* const* d_in, const int* in_sizes, int n_in,
                              void* d_out, int out_size, void* d_ws, size_t ws_size,
                              hipStream_t stream) {
    const float* vertices    = (const float*)d_in[0];
    const float* rotation    = (const float*)d_in[1];
    const float* translation = (const float*)d_in[2];
    const float* Kmat        = (const float*)d_in[3];

    const int B = in_sizes[1] / 9;              // rotation is B*3*3
    const int N = in_sizes[0] / (3 * B);        // vertices is B*N*3
    const int P = B * HW;                       // == out_size
    const int nblocks = B * NCHUNK;             // 256 blocks, 2/CU resident
    const int chunk = (((N + NCHUNK - 1) / NCHUNK) + 3) & ~3;  // 31252, %4==0

    const size_t ws_needed = (size_t)nblocks * LDSW * sizeof(unsigned int);
    const bool fits8 = ((chunk + 3) >> 2) <= 8 * BLOCK_THREADS;

    if (ws_size >= ws_needed && chunk < 65536 && (P & 3) == 0 && fits8) {
        unsigned int* ws = (unsigned int*)d_ws;
        proj16_kernel<<<nblocks, BLOCK_THREADS,
                        SWORDS * sizeof(unsigned int), stream>>>(
            vertices, rotation, translation, Kmat, ws, N, chunk);
        const int rthreads = P / 4;
        const int rblocks = (rthreads + 255) / 256;
        resolve16_kernel<<<rblocks, 256, 0, stream>>>(
            (const unsigned short*)d_ws, vertices, rotation, translation,
            (float*)d_out, N, chunk, P);
    } else {
        unsigned int* win = (unsigned int*)d_out;
        hipMemsetAsync(win, 0, (size_t)P * sizeof(unsigned int), stream);
        proj_fb_kernel<<<B * 16, BLOCK_THREADS,
                         STRIPE_PX * sizeof(unsigned int), stream>>>(
            vertices, rotation, translation, Kmat, win, N);
        const int rblocks = (P + 255) / 256;
        resolve_fb_kernel<<<rblocks, 256, 0, stream>>>(win, vertices, rotation,
                                                       translation, N, P);
    }
}

// Round 20
// 47.215 us; speedup vs baseline: 1.2436x; 1.2436x over previous
//
#include <hip/hip_runtime.h>
#include <stdint.h>

#define RH 224
#define RW 224
#define HW (RH * RW)                   // 50176 pixels
#define NCHUNK 16                      // chunks per batch; local order < 2^16
#define BLOCK_THREADS 1024
#define LDSW (HW / 2)                  // 25088 u32 words = 100352 B (u16/px)

// FP policy (FROZEN — bit-exact vs ref=np since round 8, absmax 0.0):
// numpy f32 einsum scalar tail: FORWARD accumulation, separate mul/add
// rounds, no FMA; all later elementwise ops separately rounded.
// `#pragma clang fp contract(off)` everywhere FP happens.
//
// Perf history (dur_us totals):
//  r8 389 global atomics | r9 739 guard-load REGRESS | r10 90 LDS stripes
//  x4 | r11 70 stripes x2 | r12 81 stripes x3 REGRESS | r13 86 proj-once+
//  atomic-flush REGRESS | r14 60 ws-staged flush | r15 48 full-image u16
//  LDS CAS project-once | r16 47.4 resolve vectorize == BEST | r17 50.0
//  8pt-ILP+optimistic-CAS REGRESS | r18 50.8 phase-split REGRESS |
//  r19 58.7 stripes-for-occupancy REGRESS (grid=256 kept 1 blk/CU — the
//  occupancy lever never engaged; stripe overhead paid for nothing).
//  r20: RESTORE r16 exactly. Structure is a measured local optimum:
//  project-once requires u16 full-image (100KB -> 16 waves/CU cap);
//  ILP x2, phase-split, stripes, project-twice all measured worse.

#pragma clang fp contract(off)

__device__ __forceinline__ float dot3_fwd_nofma(float v0, float v1, float v2,
                                                float R0, float R1, float R2,
                                                float t) {
#pragma clang fp contract(off)
    const float p0 = v0 * R0;
    const float p1 = v1 * R1;
    const float p2 = v2 * R2;
    float acc = p0 + p1;
    acc = acc + p2;
    acc = acc + t;
    return acc;
}

// ---------------- fast path: project once, u16 LDS z-buffer ----------------
__global__ __launch_bounds__(BLOCK_THREADS) void
proj16_kernel(const float* __restrict__ vertices,
              const float* __restrict__ rotation,
              const float* __restrict__ translation,
              const float* __restrict__ Kmat,
              unsigned int* __restrict__ ws,   // staged u16 images (as u32)
              int N, int chunk) {
#pragma clang fp contract(off)
    extern __shared__ unsigned int sbuf[];     // LDSW u32 = HW u16

    const int blk = (int)blockIdx.x;           // blk = b*NCHUNK + c
    const int c   = blk % NCHUNK;
    const int b   = blk / NCHUNK;

    // uint4 zero-init.
    {
        uint4* s4 = (uint4*)sbuf;
        const uint4 z = {0u, 0u, 0u, 0u};
        for (int j = threadIdx.x; j < LDSW / 4; j += BLOCK_THREADS) s4[j] = z;
    }
    __syncthreads();

    // Per-batch params (block-uniform -> scalar regs).
    const float* R = rotation + b * 9;
    const float* t = translation + b * 3;
    const float* k = Kmat + b * 9;
    const float fx = k[0], cx = k[2], fy = k[4], cy = k[5];
    const float R00 = R[0], R01 = R[1], R02 = R[2];
    const float R10 = R[3], R11 = R[4], R12 = R[5];
    const float R20 = R[6], R21 = R[7], R22 = R[8];
    const float t0 = t[0], t1 = t[1], t2 = t[2];

    const int n_beg  = c * chunk;              // chunk % 4 == 0 -> aligned
    const int n_end  = min(N, n_beg + chunk);
    const int nquads = (n_end - n_beg + 3) >> 2;

    for (int q = threadIdx.x; q < nquads; q += BLOCK_THREADS) {
        const int n0 = n_beg + (q << 2);
        // 4 points = 48B = 3x float4 (n0 multiple of 4 -> 16B aligned).
        const float4* vp = (const float4*)(vertices + ((size_t)b * N + n0) * 3);
        const float4 f0 = vp[0], f1 = vp[1], f2 = vp[2];
        const float pxv[4][3] = {{f0.x, f0.y, f0.z}, {f0.w, f1.x, f1.y},
                                 {f1.z, f1.w, f2.x}, {f2.y, f2.z, f2.w}};
#pragma unroll
        for (int kk = 0; kk < 4; ++kk) {
            const int n = n0 + kk;
            if (n >= n_end) break;
            const float v0 = pxv[kk][0], v1 = pxv[kk][1], v2 = pxv[kk][2];

            // FROZEN FP ORDER (single exact projection per point).
            const float y = dot3_fwd_nofma(v0, v1, v2, R10, R11, R12, t1);
            const float z = dot3_fwd_nofma(v0, v1, v2, R20, R21, R22, t2);
            const float Z = z + 1e-8f;          // separate round
            const float qy = y / Z;             // correctly-rounded div
            float w = fy * qy;                  // separate mul
            w = w + cy;                         // separate add
            const float tv = truncf(w);
            if (!(tv >= 0.0f && tv < (float)RH)) continue;  // NaN -> skip

            const float x = dot3_fwd_nofma(v0, v1, v2, R00, R01, R02, t0);
            const float qx = x / Z;
            float u = fx * qx;
            u = u + cx;
            const float tu = truncf(u);
            if (!(tu >= 0.0f && tu < (float)RW)) continue;

            const unsigned int p  = (unsigned int)((int)tv * RW + (int)tu);
            const unsigned int sh = (p & 1u) << 4;        // halfword shift
            const unsigned int val = (unsigned int)(n - n_beg + 1);  // <=chunk
            unsigned int* wp = &sbuf[p >> 1];
            unsigned int cur = *wp;
            while (((cur >> sh) & 0xFFFFu) < val) {       // u16 CAS-max
                const unsigned int nw =
                    (cur & ~(0xFFFFu << sh)) | (val << sh);
                const unsigned int prev = atomicCAS(wp, cur, nw);
                if (prev == cur) break;
                cur = prev;
            }
        }
    }
    __syncthreads();

    // Plain uint4 streaming stores into this block's private ws slice.
    uint4* dst = (uint4*)(ws + (size_t)blk * LDSW);
    const uint4* src = (const uint4*)sbuf;
    for (int j = threadIdx.x; j < LDSW / 4; j += BLOCK_THREADS)
        dst[j] = src[j];
}

// Resolve: 4 pixels/thread. Scan copies in ASCENDING chunk order; a nonzero
// later copy strictly wins -> conditional overwrite. Decode n, recompute
// depth with the frozen FP sequence.
__global__ void resolve16_kernel(const unsigned short* __restrict__ ws16,
                                 const float* __restrict__ vertices,
                                 const float* __restrict__ rotation,
                                 const float* __restrict__ translation,
                                 float* __restrict__ out, int N, int chunk,
                                 int P) {
#pragma clang fp contract(off)
    const int g = blockIdx.x * blockDim.x + threadIdx.x;   // 4-pixel group
    if (g >= P / 4) return;
    const int i0  = g << 2;
    const int b   = i0 / HW;
    const int pix = i0 - b * HW;                 // multiple of 4

    const unsigned short* base = ws16 + ((size_t)b * NCHUNK) * HW + pix;
    unsigned int m0 = 0u, m1 = 0u, m2 = 0u, m3 = 0u;
#pragma unroll
    for (int cc = 0; cc < NCHUNK; ++cc) {
        const uint2 v2 = *(const uint2*)(base + (size_t)cc * HW);
        const unsigned int ck = (unsigned int)(cc + 1) << 16;
        unsigned int v;
        v = v2.x & 0xFFFFu; if (v) m0 = ck | v;
        v = v2.x >> 16;     if (v) m1 = ck | v;
        v = v2.y & 0xFFFFu; if (v) m2 = ck | v;
        v = v2.y >> 16;     if (v) m3 = ck | v;
    }

    const unsigned int mm[4] = {m0, m1, m2, m3};
    float4 o;
    float* op = (float*)&o;
#pragma unroll
    for (int j = 0; j < 4; ++j) {
        float depth = 0.0f;
        const unsigned int m = mm[j];
        if (m != 0u) {
            const int cc = (int)(m >> 16) - 1;
            const int n  = cc * chunk + (int)(m & 0xFFFFu) - 1;
            const float* v = vertices + ((size_t)b * (size_t)N + (size_t)n) * 3;
            const float* R = rotation + b * 9;
            depth = dot3_fwd_nofma(v[0], v[1], v[2], R[6], R[7], R[8],
                                   translation[b * 3 + 2]);
        }
        op[j] = depth;
    }
    *(float4*)(out + i0) = o;
}

// ---------------- fallback path (r11: u32 LDS stripes + atomic flush) ------
#define NSTRIPE 2
#define STRIPE_ROWS (RH / NSTRIPE)
#define STRIPE_PX (STRIPE_ROWS * RW)

__global__ __launch_bounds__(BLOCK_THREADS) void
proj_fb_kernel(const float* __restrict__ vertices,
               const float* __restrict__ rotation,
               const float* __restrict__ translation,
               const float* __restrict__ Kmat,
               unsigned int* __restrict__ win, int N) {
#pragma clang fp contract(off)
    extern __shared__ unsigned int sbuf[];
    const int blk = (int)blockIdx.x;
    const int s   = blk & (NSTRIPE - 1);
    const int c   = (blk >> 1) & 7;
    const int b   = blk >> 4;
    for (int j = threadIdx.x; j < STRIPE_PX; j += BLOCK_THREADS) sbuf[j] = 0u;
    __syncthreads();
    const float* R = rotation + b * 9;
    const float* t = translation + b * 3;
    const float* k = Kmat + b * 9;
    const float fx = k[0], cx = k[2], fy = k[4], cy = k[5];
    const float R00 = R[0], R01 = R[1], R02 = R[2];
    const float R10 = R[3], R11 = R[4], R12 = R[5];
    const float R20 = R[6], R21 = R[7], R22 = R[8];
    const float t0 = t[0], t1 = t[1], t2 = t[2];
    const int chunk  = (N + 7) / 8;
    const int n_beg  = c * chunk;
    const int n_end  = min(N, n_beg + chunk);
    const int nquads = (n_end - n_beg + 3) >> 2;
    const float v_lo = (float)(s * STRIPE_ROWS);
    const float v_hi = (float)((s + 1) * STRIPE_ROWS);
    for (int q = threadIdx.x; q < nquads; q += BLOCK_THREADS) {
        const int n0 = n_beg + (q << 2);
        const float4* vp = (const float4*)(vertices + ((size_t)b * N + n0) * 3);
        const float4 f0 = vp[0], f1 = vp[1], f2 = vp[2];
        const float pxv[4][3] = {{f0.x, f0.y, f0.z}, {f0.w, f1.x, f1.y},
                                 {f1.z, f1.w, f2.x}, {f2.y, f2.z, f2.w}};
#pragma unroll
        for (int kk = 0; kk < 4; ++kk) {
            const int n = n0 + kk;
            if (n >= n_end) break;
            const float v0 = pxv[kk][0], v1 = pxv[kk][1], v2 = pxv[kk][2];
            const float y = dot3_fwd_nofma(v0, v1, v2, R10, R11, R12, t1);
            const float z = dot3_fwd_nofma(v0, v1, v2, R20, R21, R22, t2);
            const float Z = z + 1e-8f;
            const float qy = y / Z;
            float w = fy * qy;
            w = w + cy;
            const float tv = truncf(w);
            if (!(tv >= v_lo && tv < v_hi)) continue;
            const float x = dot3_fwd_nofma(v0, v1, v2, R00, R01, R02, t0);
            const float qx = x / Z;
            float u = fx * qx;
            u = u + cx;
            const float tu = truncf(u);
            if (!(tu >= 0.0f && tu < (float)RW)) continue;
            const int slot = ((int)tv - s * STRIPE_ROWS) * RW + (int)tu;
            atomicMax(&sbuf[slot], (unsigned int)(b * N + n) + 1u);
        }
    }
    __syncthreads();
    unsigned int* g = win + b * HW + s * STRIPE_PX;
    for (int j = threadIdx.x; j < STRIPE_PX; j += BLOCK_THREADS) {
        const unsigned int val = sbuf[j];
        if (val) atomicMax(&g[j], val);
    }
}

__global__ void resolve_fb_kernel(unsigned int* __restrict__ buf,
                                  const float* __restrict__ vertices,
                                  const float* __restrict__ rotation,
                                  const float* __restrict__ translation,
                                  int N, int P) {
#pragma clang fp contract(off)
    const int i = blockIdx.x * blockDim.x + threadIdx.x;
    if (i >= P) return;
    const unsigned int o1 = buf[i];
    float depth = 0.0f;
    if (o1 != 0u) {
        const unsigned int o = o1 - 1u;
        const int b = (int)(o / (unsigned int)N);
        const int n = (int)(o % (unsigned int)N);
        const float* v = vertices + ((size_t)b * (size_t)N + (size_t)n) * 3;
        const float* R = rotation + b * 9;
        depth = dot3_fwd_nofma(v[0], v[1], v[2], R[6], R[7], R[8],
                               translation[b * 3 + 2]);
    }
    buf[i] = __float_as_uint(depth);
}

extern "C" void kernel_launch(void* const* d_in, const int* in_sizes, int n_in,
                              void* d_out, int out_size, void* d_ws, size_t ws_size,
                              hipStream_t stream) {
    const float* vertices    = (const float*)d_in[0];
    const float* rotation    = (const float*)d_in[1];
    const float* translation = (const float*)d_in[2];
    const float* Kmat        = (const float*)d_in[3];

    const int B = in_sizes[1] / 9;              // rotation is B*3*3
    const int N = in_sizes[0] / (3 * B);        // vertices is B*N*3
    const int P = B * HW;                       // == out_size
    const int nblocks = B * NCHUNK;             // 256 = 1 block/CU
    const int chunk = (((N + NCHUNK - 1) / NCHUNK) + 3) & ~3;  // 31252, %4==0

    const size_t ws_needed = (size_t)nblocks * LDSW * sizeof(unsigned int);

    if (ws_size >= ws_needed && chunk < 65536 && (P & 3) == 0) {
        unsigned int* ws = (unsigned int*)d_ws;
        proj16_kernel<<<nblocks, BLOCK_THREADS,
                        LDSW * sizeof(unsigned int), stream>>>(
            vertices, rotation, translation, Kmat, ws, N, chunk);
        const int rthreads = P / 4;
        const int rblocks = (rthreads + 255) / 256;
        resolve16_kernel<<<rblocks, 256, 0, stream>>>(
            (const unsigned short*)d_ws, vertices, rotation, translation,
            (float*)d_out, N, chunk, P);
    } else {
        unsigned int* win = (unsigned int*)d_out;
        hipMemsetAsync(win, 0, (size_t)P * sizeof(unsigned int), stream);
        proj_fb_kernel<<<B * 16, BLOCK_THREADS,
                         STRIPE_PX * sizeof(unsigned int), stream>>>(
            vertices, rotation, translation, Kmat, win, N);
        const int rblocks = (P + 255) / 256;
        resolve_fb_kernel<<<rblocks, 256, 0, stream>>>(win, vertices, rotation,
                                                       translation, N, P);
    }
}